// Round 5
// baseline (1365.139 us; speedup 1.0000x reference)
//
#include <hip/hip_runtime.h>
#include <hip/hip_cooperative_groups.h>
#include <cmath>
#include <stdint.h>

namespace cg = cooperative_groups;

// ---------------------------------------------------------------------------
// AttentionLayer: att = softmax((q@W1+b1) @ (k@W2+b2)^T / sqrt(Sk)) @ v
// B=4, SQ=SK=2048, D=UNITS=1024, fp32 in/out, bf16 MFMA internally.
// R5: single cooperative mega-kernel (prep -> l1l2 -> score+exp -> att/div)
//     with grid.sync() + agent fences between phases. Partial-slot rowsums
//     (no atomics, no memset). Fallback to split kernels if coop launch fails.
// ---------------------------------------------------------------------------

typedef short short8 __attribute__((ext_vector_type(8)));
typedef float f32x4 __attribute__((ext_vector_type(4)));
typedef __bf16 bf16x8 __attribute__((ext_vector_type(8)));

typedef __attribute__((address_space(3))) void lds_void;
typedef __attribute__((address_space(1))) void gbl_void;

__device__ __forceinline__ unsigned short f2b(float x) {
    unsigned u = __builtin_bit_cast(unsigned, x);
    u += 0x7fffu + ((u >> 16) & 1u);
    return (unsigned short)(u >> 16);
}

struct KParams {
    const float *q, *k, *v, *W1, *W2, *b1, *b2;
    float* out;
    unsigned short *qbf, *kbf, *vT, *W1t, *W2t, *l1, *l2, *sc;
    float* partial;   // [4][2048][32] per-row partial exp-sums
};

__device__ __forceinline__ void load16_to_lds(const unsigned short* g,
                                              unsigned short* l) {
    __builtin_amdgcn_global_load_lds((gbl_void*)g, (lds_void*)l, 16, 0, 0);
}

// ---------------------------------------------------------------------------
// Phase 0: prep. 20480 virtual blocks of work, looped. vz: 0..3 v-transpose,
// 4..5 W1/W2 transpose, 6..9 q/k cast.
// ---------------------------------------------------------------------------
__device__ __forceinline__ void prep_phase(int blk, const KParams& p,
                                           unsigned short* As) {
    float (*tile)[33] = (float (*)[33])(void*)As;
    const int t = threadIdx.x;
    for (int it = 0; it < 20; ++it) {
        const int vb = it * 1024 + blk;
        const int vz = vb >> 11;
        const int rem = vb & 2047;
        const int vy = rem >> 6;
        const int vx = rem & 63;
        if (vz >= 6) {
            // ---- cast path: 2048 elems per virtual block ----
            const float* in = (vz < 8) ? p.q : p.k;
            unsigned short* outp = (vz < 8) ? p.qbf : p.kbf;
            const long zi = (vz - 6) & 1;
            const long fb = zi * 2048 + vy * 64 + vx;
            const long i = (fb * 256 + t) * 8;
            float4 a = *(const float4*)(in + i);
            float4 b = *(const float4*)(in + i + 4);
            union { short8 v8; unsigned short u[8]; } r;
            r.u[0] = f2b(a.x); r.u[1] = f2b(a.y); r.u[2] = f2b(a.z); r.u[3] = f2b(a.w);
            r.u[4] = f2b(b.x); r.u[5] = f2b(b.y); r.u[6] = f2b(b.z); r.u[7] = f2b(b.w);
            *(short8*)(outp + i) = r.v8;
        } else {
            // ---- transpose path ----
            const float* in;
            unsigned short* outp;
            int R, C;
            bool act = true;
            if (vz < 4) {
                R = 2048; C = 1024;
                in = p.v + (long)vz * R * C;
                outp = p.vT + (long)vz * R * C;
            } else {
                R = 1024; C = 1024;
                act = (vx < 32);
                in = (vz == 4) ? p.W1 : p.W2;
                outp = (vz == 4) ? p.W1t : p.W2t;
            }
            const int rt = vx * 32, ct = vy * 32;
            if (act) {
                int r = t >> 3, c4 = (t & 7) * 4;
                float4 a = *(const float4*)(in + (long)(rt + r) * C + ct + c4);
                tile[r][c4 + 0] = a.x; tile[r][c4 + 1] = a.y;
                tile[r][c4 + 2] = a.z; tile[r][c4 + 3] = a.w;
            }
            __syncthreads();
            if (act) {
                int c = t >> 3, rg = (t & 7) * 4;
                ushort4 o;
                o.x = f2b(tile[rg + 0][c]); o.y = f2b(tile[rg + 1][c]);
                o.z = f2b(tile[rg + 2][c]); o.w = f2b(tile[rg + 3][c]);
                *(ushort4*)(outp + (long)(ct + c) * R + rt + rg) = o;
            }
        }
        __syncthreads();
    }
}

// ---------------------------------------------------------------------------
// GEMM phase: C[M][N] = A[M][K] * Bt[N][K]^T, 128x128 tile, BK=64,
// 4 waves (2x2), 4x4 16x16x32 MFMA per sub-k. LDS XOR swizzle, XCD stripe
// remap over virtual grid (nx, ny, nz) from flat id.
// MODE 0: bf16 out + bias (bias1 when bz==1)     [l1/l2]
// MODE 1: bf16 out = exp(acc*scale), partial[row][bx*2+wn] = lr-sum  [score]
// MODE 2: fp32 out = acc / sum32(partial[row])   [att]
// ---------------------------------------------------------------------------
template <int MODE>
__device__ __forceinline__ void gemm_phase(
        int flat, int nx, int ny, int nz,
        const unsigned short* __restrict__ A0,
        const unsigned short* __restrict__ Bt0,
        const float* __restrict__ bias0, const float* __restrict__ bias1,
        const float* __restrict__ part_in, float* __restrict__ part_out,
        void* __restrict__ Cout,
        int M, int N, int K, float scale,
        long sA, long sB, long sC,
        unsigned short* As, unsigned short* Bs) {
    // ---- XCD-aware tile remap (Rt = ny*nz always divisible by 8 here) ----
    int bx, by, bz;
    {
        const int Rt = ny * nz;
        int rpx = Rt >> 3;
        int c = flat & 7;
        int j = flat >> 3;
        bx = j / rpx;
        int yg = c * rpx + (j - bx * rpx);
        bz = yg / ny;
        by = yg - bz * ny;
    }
    const unsigned short* A  = A0  + (long)bz * sA;
    const unsigned short* Bt = Bt0 + (long)bz * sB;

    const int t = threadIdx.x;
    const int lane = t & 63;
    const int wave = t >> 6;
    const int wm = wave >> 1, wn = wave & 1;
    const int row0 = by * 128;
    const int col0 = bx * 128;

    const int rS = lane >> 3;
    const int kOffS = ((lane & 7) ^ rS) * 8;
    const unsigned short* gA[4];
    const unsigned short* gB[4];
    unsigned short* lA[4];
    unsigned short* lB[4];
#pragma unroll
    for (int i = 0; i < 4; i++) {
        const int rowl = i * 32 + wave * 8 + rS;
        const int ldsrow = i * 32 + wave * 8;
        gA[i] = A  + (long)(row0 + rowl) * K + kOffS;
        gB[i] = Bt + (long)(col0 + rowl) * K + kOffS;
        lA[i] = As + ldsrow * 64;
        lB[i] = Bs + ldsrow * 64;
    }

    const int lr = lane & 15;
    const int quad = lane >> 4;
    const int pc0 = (quad ^ (lr & 7)) * 8;
    const int pc1 = ((4 + quad) ^ (lr & 7)) * 8;

    f32x4 acc[4][4];
#pragma unroll
    for (int i = 0; i < 4; i++)
#pragma unroll
        for (int j = 0; j < 4; j++) acc[i][j] = f32x4{0.f, 0.f, 0.f, 0.f};

    for (int k0 = 0; k0 < K; k0 += 64) {
#pragma unroll
        for (int i = 0; i < 4; i++) {
            load16_to_lds(gA[i] + k0, lA[i]);
            load16_to_lds(gB[i] + k0, lB[i]);
        }
        __syncthreads();
#pragma unroll
        for (int ks = 0; ks < 2; ks++) {
            const int pc = ks ? pc1 : pc0;
            bf16x8 a[4], b[4];
#pragma unroll
            for (int i = 0; i < 4; i++) {
                a[i] = __builtin_bit_cast(bf16x8,
                    *(const short8*)(As + (wm * 64 + i * 16 + lr) * 64 + pc));
                b[i] = __builtin_bit_cast(bf16x8,
                    *(const short8*)(Bs + (wn * 64 + i * 16 + lr) * 64 + pc));
            }
#pragma unroll
            for (int i = 0; i < 4; i++)
#pragma unroll
                for (int j = 0; j < 4; j++)
                    acc[i][j] = __builtin_amdgcn_mfma_f32_16x16x32_bf16(
                        a[i], b[j], acc[i][j], 0, 0, 0);
        }
        __syncthreads();
    }

    // ---- epilogue (C/D layout: col = lane&15, row = quad*4 + reg) ----
    const long cbase = (long)bz * sC;

    if (MODE == 0) {
        const float* bp = (bz && bias1) ? bias1 : bias0;
#pragma unroll
        for (int j = 0; j < 4; j++) {
            const int gcol = col0 + wn * 64 + j * 16 + lr;
            const float bv = bp[gcol];
#pragma unroll
            for (int i = 0; i < 4; i++) {
                const int growb = row0 + wm * 64 + i * 16 + quad * 4;
#pragma unroll
                for (int r = 0; r < 4; r++) {
                    float val = acc[i][j][r] * scale + bv;
                    ((unsigned short*)Cout)[cbase + (long)(growb + r) * N + gcol] = f2b(val);
                }
            }
        }
    } else if (MODE == 1) {
        float psum[4][4];
#pragma unroll
        for (int i = 0; i < 4; i++)
#pragma unroll
            for (int r = 0; r < 4; r++) psum[i][r] = 0.f;
#pragma unroll
        for (int j = 0; j < 4; j++) {
            const int gcol = col0 + wn * 64 + j * 16 + lr;
#pragma unroll
            for (int i = 0; i < 4; i++) {
                const int growb = row0 + wm * 64 + i * 16 + quad * 4;
#pragma unroll
                for (int r = 0; r < 4; r++) {
                    float e = __expf(acc[i][j][r] * scale);
                    psum[i][r] += e;
                    ((unsigned short*)Cout)[cbase + (long)(growb + r) * N + gcol] = f2b(e);
                }
            }
        }
#pragma unroll
        for (int i = 0; i < 4; i++)
#pragma unroll
            for (int r = 0; r < 4; r++) {
                float s = psum[i][r];
                s += __shfl_xor(s, 1);
                s += __shfl_xor(s, 2);
                s += __shfl_xor(s, 4);
                s += __shfl_xor(s, 8);
                if (lr == 0) {
                    const int grow = row0 + wm * 64 + i * 16 + quad * 4 + r;
                    part_out[((long)bz * 2048 + grow) * 32 + bx * 2 + wn] = s;
                }
            }
    } else {  // MODE == 2
        // cooperative rowsum reduction into LDS (As is free after K-loop)
        float* rowinv = (float*)(void*)As;
        if (t < 128) {
            const float* pr = part_in + ((long)bz * 2048 + row0 + t) * 32;
            float s = 0.f;
#pragma unroll
            for (int c4 = 0; c4 < 32; c4 += 4) {
                float4 v4 = *(const float4*)(pr + c4);
                s += v4.x + v4.y + v4.z + v4.w;
            }
            rowinv[t] = 1.0f / s;
        }
        __syncthreads();
#pragma unroll
        for (int i = 0; i < 4; i++) {
            const int lrow = wm * 64 + i * 16 + quad * 4;
#pragma unroll
            for (int r = 0; r < 4; r++) {
                const float inv = rowinv[lrow + r];
#pragma unroll
                for (int j = 0; j < 4; j++) {
                    const int gcol = col0 + wn * 64 + j * 16 + lr;
                    ((float*)Cout)[cbase + (long)(row0 + lrow + r) * N + gcol] =
                        acc[i][j][r] * inv;
                }
            }
        }
        __syncthreads();   // protect As reuse semantics for callers
    }
}

// ---------------------------------------------------------------------------
// Mega kernel: all phases + grid syncs. grid = 1024 x 256, 4 blocks/CU.
// ---------------------------------------------------------------------------
__global__ __launch_bounds__(256, 4) void mega_kernel(KParams p) {
    __shared__ __align__(16) unsigned short As[128 * 64];
    __shared__ __align__(16) unsigned short Bs[128 * 64];
    cg::grid_group grid = cg::this_grid();
    const int blk = blockIdx.x;
    const float invs = 0.02209708691207961f;   // 1/sqrt(2048)

    // P0: prep
    prep_phase(blk, p, As);
    __threadfence(); grid.sync(); __threadfence();

    // P1: l1 = q@W1+b1 (bz=0), l2 = k@W2+b2 (bz=1)
    gemm_phase<0>(blk, 8, 64, 2, p.qbf, p.W1t, p.b1, p.b2, nullptr, nullptr,
                  p.l1, 8192, 1024, 1024, 1.0f,
                  8L * 1024 * 1024, 1L * 1024 * 1024, 8L * 1024 * 1024, As, Bs);
    __threadfence(); grid.sync(); __threadfence();

    // P2: sc = exp(l1 @ l2^T * invs), partial rowsums
    gemm_phase<1>(blk, 16, 16, 4, p.l1, p.l2, nullptr, nullptr, nullptr,
                  p.partial, p.sc, 2048, 2048, 1024, invs,
                  2L * 1024 * 1024, 2L * 1024 * 1024, 4L * 1024 * 1024, As, Bs);
    __threadfence(); grid.sync(); __threadfence();

    // P3: att = (sc @ vT^T) / rowsum
    if (blk < 512) {
        gemm_phase<2>(blk, 8, 16, 4, p.sc, p.vT, nullptr, nullptr,
                      p.partial, nullptr, p.out, 2048, 1024, 2048, 1.0f,
                      4L * 1024 * 1024, 2L * 1024 * 1024, 2L * 1024 * 1024, As, Bs);
    }
}

// ---------------------------------------------------------------------------
// Fallback split kernels (same device code, separate launches)
// ---------------------------------------------------------------------------
__global__ __launch_bounds__(256, 4) void prep_only_kernel(KParams p) {
    __shared__ __align__(16) unsigned short As[128 * 64];
    prep_phase(blockIdx.x, p, As);
}
__global__ __launch_bounds__(256, 4) void l1l2_kernel(KParams p) {
    __shared__ __align__(16) unsigned short As[128 * 64];
    __shared__ __align__(16) unsigned short Bs[128 * 64];
    gemm_phase<0>(blockIdx.x, 8, 64, 2, p.qbf, p.W1t, p.b1, p.b2, nullptr,
                  nullptr, p.l1, 8192, 1024, 1024, 1.0f,
                  8L * 1024 * 1024, 1L * 1024 * 1024, 8L * 1024 * 1024, As, Bs);
}
__global__ __launch_bounds__(256, 4) void score_kernel(KParams p) {
    __shared__ __align__(16) unsigned short As[128 * 64];
    __shared__ __align__(16) unsigned short Bs[128 * 64];
    gemm_phase<1>(blockIdx.x, 16, 16, 4, p.l1, p.l2, nullptr, nullptr, nullptr,
                  p.partial, p.sc, 2048, 2048, 1024, 0.02209708691207961f,
                  2L * 1024 * 1024, 2L * 1024 * 1024, 4L * 1024 * 1024, As, Bs);
}
__global__ __launch_bounds__(256, 4) void att_kernel(KParams p) {
    __shared__ __align__(16) unsigned short As[128 * 64];
    __shared__ __align__(16) unsigned short Bs[128 * 64];
    gemm_phase<2>(blockIdx.x, 8, 16, 4, p.sc, p.vT, nullptr, nullptr,
                  p.partial, nullptr, p.out, 2048, 1024, 2048, 1.0f,
                  4L * 1024 * 1024, 2L * 1024 * 1024, 2L * 1024 * 1024, As, Bs);
}

// ---------------------------------------------------------------------------
extern "C" void kernel_launch(void* const* d_in, const int* in_sizes, int n_in,
                              void* d_out, int out_size, void* d_ws, size_t ws_size,
                              hipStream_t stream) {
    char* ws = (char*)d_ws;
    const size_t MB = 1024 * 1024;
    KParams p;
    p.q   = (const float*)d_in[0];
    p.k   = (const float*)d_in[1];
    p.v   = (const float*)d_in[2];
    p.W1  = (const float*)d_in[3];
    p.b1  = (const float*)d_in[4];
    p.W2  = (const float*)d_in[5];
    p.b2  = (const float*)d_in[6];
    p.out = (float*)d_out;
    p.qbf = (unsigned short*)(ws + 0);        // 16 MB
    p.kbf = (unsigned short*)(ws + 16 * MB);  // 16 MB
    p.vT  = (unsigned short*)(ws + 32 * MB);  // 16 MB [B][D][SK]
    p.W1t = (unsigned short*)(ws + 48 * MB);  // 2 MB  [U][D] (dead after P1)
    p.W2t = (unsigned short*)(ws + 50 * MB);  // 2 MB  (dead after P1)
    p.l1  = (unsigned short*)(ws + 52 * MB);  // 16 MB [B*SQ][U]
    p.l2  = (unsigned short*)(ws + 68 * MB);  // 16 MB
    p.sc  = (unsigned short*)(ws + 0);        // 32 MB [B][SQ][SK] (aliases qbf/kbf)
    p.partial = (float*)(ws + 48 * MB);       // 1 MB [4][2048][32] (reuses W1t slot)

    void* args[] = { &p };
    hipError_t e = hipLaunchCooperativeKernel(
        reinterpret_cast<void*>(mega_kernel), dim3(1024), dim3(256),
        args, 0, stream);
    if (e != hipSuccess) {
        // fallback: split launches (same device code, no grid sync needed --
        // kernel boundaries provide cross-XCD visibility)
        prep_only_kernel<<<1024, 256, 0, stream>>>(p);
        l1l2_kernel<<<1024, 256, 0, stream>>>(p);
        score_kernel<<<1024, 256, 0, stream>>>(p);
        att_kernel<<<512, 256, 0, stream>>>(p);
    }
}

// Round 6
// 400.014 us; speedup vs baseline: 3.4127x; 3.4127x over previous
//
#include <hip/hip_runtime.h>
#include <cmath>
#include <stdint.h>

// ---------------------------------------------------------------------------
// AttentionLayer: att = softmax((q@W1+b1) @ (k@W2+b2)^T / sqrt(Sk)) @ v
// B=4, SQ=SK=2048, D=UNITS=1024, fp32 in/out, bf16 MFMA internally.
// R6: algebraic refactor -- score = q (W1 W2^T) k^T; row-constant bias terms
//     cancel under softmax, only vv = k@W2@b1 survives (added per column).
//     4 dispatches: prep(+Mt GEMM+w2b1) -> tq(+vv) -> score(exp+partials)
//     -> att(/rowsum). Partial-slot rowsums (no memset). No grid sync (R5's
//     coop fences caused L2 writeback storms -- 5x regression, reverted).
// ---------------------------------------------------------------------------

typedef short short8 __attribute__((ext_vector_type(8)));
typedef float f32x4 __attribute__((ext_vector_type(4)));
typedef __bf16 bf16x8 __attribute__((ext_vector_type(8)));

typedef __attribute__((address_space(3))) void lds_void;
typedef __attribute__((address_space(1))) void gbl_void;

__device__ __forceinline__ unsigned short f2b(float x) {
    unsigned u = __builtin_bit_cast(unsigned, x);
    u += 0x7fffu + ((u >> 16) & 1u);
    return (unsigned short)(u >> 16);
}
__device__ __forceinline__ float b2f(unsigned short x) {
    unsigned u = ((unsigned)x) << 16;
    return __builtin_bit_cast(float, u);
}

struct Off4 { long o[4]; };

__device__ __forceinline__ void load16_to_lds(const unsigned short* g,
                                              unsigned short* l) {
    __builtin_amdgcn_global_load_lds((gbl_void*)g, (lds_void*)l, 16, 0, 0);
}

// ---------------------------------------------------------------------------
// MFMA over staged 128x64 LDS tiles (XOR layout: phys chunk = logical^(row&7))
// ---------------------------------------------------------------------------
__device__ __forceinline__ void mfma_tile(const unsigned short* As,
                                          const unsigned short* Bs,
                                          int wm, int wn, int lr, int quad,
                                          f32x4 acc[4][4]) {
    const int pc0 = (quad ^ (lr & 7)) * 8;
    const int pc1 = ((4 + quad) ^ (lr & 7)) * 8;
#pragma unroll
    for (int ks = 0; ks < 2; ks++) {
        const int pc = ks ? pc1 : pc0;
        bf16x8 a[4], b[4];
#pragma unroll
        for (int i = 0; i < 4; i++) {
            a[i] = __builtin_bit_cast(bf16x8,
                *(const short8*)(As + (wm * 64 + i * 16 + lr) * 64 + pc));
            b[i] = __builtin_bit_cast(bf16x8,
                *(const short8*)(Bs + (wn * 64 + i * 16 + lr) * 64 + pc));
        }
#pragma unroll
        for (int i = 0; i < 4; i++)
#pragma unroll
            for (int j = 0; j < 4; j++)
                acc[i][j] = __builtin_amdgcn_mfma_f32_16x16x32_bf16(
                    a[i], b[j], acc[i][j], 0, 0, 0);
    }
}

// ---------------------------------------------------------------------------
// bf16 GEMM core: C = A @ Bt^T, 128x128 tile, BK=64, 4 waves (2x2).
// A base per batch via Off4 (elem offsets); Bt via stride; C via Off4.
// MODE 0: bf16 out                          [tq]
// MODE 1: bf16 out = exp((acc+vv[col])*scale), partial[row][bx*2+wn]  [score]
// MODE 2: fp32 out = acc / sum32(partial[row])                        [att]
// ---------------------------------------------------------------------------
template <int MODE>
__device__ __forceinline__ void gemm_core(
        int flat, int nx, int ny, int nz,
        const unsigned short* __restrict__ A0, Off4 aoff,
        const unsigned short* __restrict__ Bt0, long sB,
        const float* __restrict__ vv, float* __restrict__ partial,
        void* __restrict__ C0, Off4 coff,
        int N, int K, float scale,
        unsigned short* As, unsigned short* Bs) {
    // ---- XCD-aware tile remap (Rt = ny*nz divisible by 8) ----
    int bx, by, bz;
    {
        const int Rt = ny * nz;
        int rpx = Rt >> 3;
        int c = flat & 7;
        int j = flat >> 3;
        bx = j / rpx;
        int yg = c * rpx + (j - bx * rpx);
        bz = yg / ny;
        by = yg - bz * ny;
    }
    const unsigned short* A  = A0  + aoff.o[bz];
    const unsigned short* Bt = Bt0 + (long)bz * sB;

    const int t = threadIdx.x;
    const int lane = t & 63;
    const int wave = t >> 6;
    const int wm = wave >> 1, wn = wave & 1;
    const int row0 = by * 128;
    const int col0 = bx * 128;

    const int rS = lane >> 3;
    const int kOffS = ((lane & 7) ^ rS) * 8;
    const unsigned short* gA[4];
    const unsigned short* gB[4];
    unsigned short* lA[4];
    unsigned short* lB[4];
#pragma unroll
    for (int i = 0; i < 4; i++) {
        const int rowl = i * 32 + wave * 8 + rS;
        const int ldsrow = i * 32 + wave * 8;
        gA[i] = A  + (long)(row0 + rowl) * K + kOffS;
        gB[i] = Bt + (long)(col0 + rowl) * K + kOffS;
        lA[i] = As + ldsrow * 64;
        lB[i] = Bs + ldsrow * 64;
    }

    const int lr = lane & 15;
    const int quad = lane >> 4;

    f32x4 acc[4][4];
#pragma unroll
    for (int i = 0; i < 4; i++)
#pragma unroll
        for (int j = 0; j < 4; j++) acc[i][j] = f32x4{0.f, 0.f, 0.f, 0.f};

    for (int k0 = 0; k0 < K; k0 += 64) {
#pragma unroll
        for (int i = 0; i < 4; i++) {
            load16_to_lds(gA[i] + k0, lA[i]);
            load16_to_lds(gB[i] + k0, lB[i]);
        }
        __syncthreads();
        mfma_tile(As, Bs, wm, wn, lr, quad, acc);
        __syncthreads();
    }

    // ---- epilogue (C/D layout: col = lane&15, row = quad*4 + reg) ----
    const long cbase = coff.o[bz];

    if (MODE == 0) {
#pragma unroll
        for (int j = 0; j < 4; j++) {
            const int gcol = col0 + wn * 64 + j * 16 + lr;
#pragma unroll
            for (int i = 0; i < 4; i++) {
                const int growb = row0 + wm * 64 + i * 16 + quad * 4;
#pragma unroll
                for (int r = 0; r < 4; r++)
                    ((unsigned short*)C0)[cbase + (long)(growb + r) * N + gcol] =
                        f2b(acc[i][j][r]);
            }
        }
    } else if (MODE == 1) {
        float psum[4][4];
#pragma unroll
        for (int i = 0; i < 4; i++)
#pragma unroll
            for (int r = 0; r < 4; r++) psum[i][r] = 0.f;
#pragma unroll
        for (int j = 0; j < 4; j++) {
            const int gcol = col0 + wn * 64 + j * 16 + lr;
            const float vvv = vv[(long)bz * 2048 + gcol];
#pragma unroll
            for (int i = 0; i < 4; i++) {
                const int growb = row0 + wm * 64 + i * 16 + quad * 4;
#pragma unroll
                for (int r = 0; r < 4; r++) {
                    float e = __expf((acc[i][j][r] + vvv) * scale);
                    psum[i][r] += e;
                    ((unsigned short*)C0)[cbase + (long)(growb + r) * N + gcol] = f2b(e);
                }
            }
        }
#pragma unroll
        for (int i = 0; i < 4; i++)
#pragma unroll
            for (int r = 0; r < 4; r++) {
                float s = psum[i][r];
                s += __shfl_xor(s, 1);
                s += __shfl_xor(s, 2);
                s += __shfl_xor(s, 4);
                s += __shfl_xor(s, 8);
                if (lr == 0) {
                    const int grow = row0 + wm * 64 + i * 16 + quad * 4 + r;
                    partial[((long)bz * 2048 + grow) * 32 + bx * 2 + wn] = s;
                }
            }
    } else {  // MODE == 2
        float* rowinv = (float*)(void*)As;
        if (t < 128) {
            const float* pr = partial + ((long)bz * 2048 + row0 + t) * 32;
            float s = 0.f;
#pragma unroll
            for (int c4 = 0; c4 < 32; c4 += 4) {
                float4 v4 = *(const float4*)(pr + c4);
                s += v4.x + v4.y + v4.z + v4.w;
            }
            rowinv[t] = 1.0f / s;
        }
        __syncthreads();
#pragma unroll
        for (int i = 0; i < 4; i++) {
            const int lrow = wm * 64 + i * 16 + quad * 4;
#pragma unroll
            for (int r = 0; r < 4; r++) {
                const float inv = rowinv[lrow + r];
#pragma unroll
                for (int j = 0; j < 4; j++) {
                    const int gcol = col0 + wn * 64 + j * 16 + lr;
                    ((float*)C0)[cbase + (long)(row0 + lrow + r) * N + gcol] =
                        acc[i][j][r] * inv;
                }
            }
        }
    }
}

// ---------------------------------------------------------------------------
// prep kernel: grid x = 16480.
//   0..63    : Mt = W2 @ W1^T  (fp32 hybrid staging, bf16 MFMA, 128x128 tiles)
//   64..95   : w2b1[d'] = dot(W2[d',:], b1)
//   96..8287 : v batch transpose  [2048][1024] -> vT [1024][2048] bf16
//   8288..   : q,k fp32 -> bf16 casts (4096 blocks each)
// ---------------------------------------------------------------------------
__global__ void prep_kernel(const float* __restrict__ q,
                            const float* __restrict__ k,
                            const float* __restrict__ v,
                            const float* __restrict__ W1,
                            const float* __restrict__ W2,
                            const float* __restrict__ b1,
                            unsigned short* __restrict__ qbf,
                            unsigned short* __restrict__ kbf,
                            unsigned short* __restrict__ vT,
                            unsigned short* __restrict__ Mt,
                            float* __restrict__ w2b1) {
    __shared__ __align__(16) unsigned short As[128 * 64];
    __shared__ __align__(16) unsigned short Bs[128 * 64];
    const int flat = blockIdx.x;
    const int t = threadIdx.x;

    if (flat < 64) {
        // ---- Mt GEMM: A = W2 (rows d'), Bt = W1 (rows d), K = u = 1024 ----
        const int by = flat >> 3, bx = flat & 7;
        const int row0 = by * 128, col0 = bx * 128;
        const int lane = t & 63, wave = t >> 6;
        const int wm = wave >> 1, wn = wave & 1;
        const int lr = lane & 15, quad = lane >> 4;
        const int srow = t >> 1;            // 0..127
        const int hk = (t & 1) * 32;        // fp32 elems 0 or 32
        const float* gA = W2 + (long)(row0 + srow) * 1024 + hk;
        const float* gB = W1 + (long)(col0 + srow) * 1024 + hk;
        unsigned short* lA = As + srow * 64;
        unsigned short* lB = Bs + srow * 64;
        const int xr = srow & 7;

        f32x4 acc[4][4];
#pragma unroll
        for (int i = 0; i < 4; i++)
#pragma unroll
            for (int j = 0; j < 4; j++) acc[i][j] = f32x4{0.f, 0.f, 0.f, 0.f};

        for (int k0 = 0; k0 < 1024; k0 += 64) {
#pragma unroll
            for (int m2 = 0; m2 < 2; m2++) {
                const float* src = m2 ? gB : gA;
                unsigned short* dst = m2 ? lB : lA;
#pragma unroll
                for (int ci = 0; ci < 4; ci++) {
                    float4 f0 = *(const float4*)(src + k0 + ci * 8);
                    float4 f1 = *(const float4*)(src + k0 + ci * 8 + 4);
                    union { short8 v8; unsigned short u[8]; } r;
                    r.u[0] = f2b(f0.x); r.u[1] = f2b(f0.y);
                    r.u[2] = f2b(f0.z); r.u[3] = f2b(f0.w);
                    r.u[4] = f2b(f1.x); r.u[5] = f2b(f1.y);
                    r.u[6] = f2b(f1.z); r.u[7] = f2b(f1.w);
                    const int phys = ((hk >> 3) + ci) ^ xr;
                    *(short8*)(dst + phys * 8) = r.v8;
                }
            }
            __syncthreads();
            mfma_tile(As, Bs, wm, wn, lr, quad, acc);
            __syncthreads();
        }
#pragma unroll
        for (int j = 0; j < 4; j++) {
            const int gcol = col0 + wn * 64 + j * 16 + lr;
#pragma unroll
            for (int i = 0; i < 4; i++) {
                const int growb = row0 + wm * 64 + i * 16 + quad * 4;
#pragma unroll
                for (int r = 0; r < 4; r++)
                    Mt[(long)(growb + r) * 1024 + gcol] = f2b(acc[i][j][r]);
            }
        }
        return;
    }
    if (flat < 96) {
        // ---- w2b1 = W2 @ b1 ----
        const int b = flat - 64;
        const int row = b * 32 + (t >> 3);
        const int oct = t & 7;
        const float* wr = W2 + (long)row * 1024 + oct * 128;
        const float* br = b1 + oct * 128;
        float s = 0.f;
#pragma unroll
        for (int i = 0; i < 32; i++) {
            float4 w = *(const float4*)(wr + i * 4);
            float4 bb = *(const float4*)(br + i * 4);
            s += w.x * bb.x + w.y * bb.y + w.z * bb.z + w.w * bb.w;
        }
        s += __shfl_xor(s, 1);
        s += __shfl_xor(s, 2);
        s += __shfl_xor(s, 4);
        if (oct == 0) w2b1[row] = s;
        return;
    }
    const int u = flat - 96;
    if (u < 8192) {
        // ---- v transpose: [2048][1024] -> [1024][2048] ----
        float (*tile)[33] = (float (*)[33])(void*)As;
        const int vz = u >> 11;
        const int rem = u & 2047;
        const int vy = rem >> 6, vx = rem & 63;
        const float* in = v + (long)vz * 2048 * 1024;
        unsigned short* outp = vT + (long)vz * 1024 * 2048;
        const int rt = vx * 32, ct = vy * 32;
        {
            int r = t >> 3, c4 = (t & 7) * 4;
            float4 a = *(const float4*)(in + (long)(rt + r) * 1024 + ct + c4);
            tile[r][c4 + 0] = a.x; tile[r][c4 + 1] = a.y;
            tile[r][c4 + 2] = a.z; tile[r][c4 + 3] = a.w;
        }
        __syncthreads();
        {
            int c = t >> 3, rg = (t & 7) * 4;
            ushort4 o;
            o.x = f2b(tile[rg + 0][c]); o.y = f2b(tile[rg + 1][c]);
            o.z = f2b(tile[rg + 2][c]); o.w = f2b(tile[rg + 3][c]);
            *(ushort4*)(outp + (long)(ct + c) * 2048 + rt + rg) = o;
        }
        return;
    }
    // ---- q/k casts: 2048 elems per block ----
    const int c = u - 8192;
    const float* in = (c < 4096) ? q : k;
    unsigned short* outp = (c < 4096) ? qbf : kbf;
    const long i = (((long)(c & 4095)) * 256 + t) * 8;
    float4 a = *(const float4*)(in + i);
    float4 b = *(const float4*)(in + i + 4);
    union { short8 v8; unsigned short uu[8]; } r;
    r.uu[0] = f2b(a.x); r.uu[1] = f2b(a.y); r.uu[2] = f2b(a.z); r.uu[3] = f2b(a.w);
    r.uu[4] = f2b(b.x); r.uu[5] = f2b(b.y); r.uu[6] = f2b(b.z); r.uu[7] = f2b(b.w);
    *(short8*)(outp + i) = r.v8;
}

// ---------------------------------------------------------------------------
// tq kernel: 0..511 tq = qbf @ Mt^T; 512..575 vv[n] = dot(kbf[n,:], w2b1)
// ---------------------------------------------------------------------------
__global__ void tq_kernel(const unsigned short* __restrict__ qbf,
                          const unsigned short* __restrict__ Mt,
                          const unsigned short* __restrict__ kbf,
                          const float* __restrict__ w2b1,
                          unsigned short* __restrict__ tq,
                          float* __restrict__ vv) {
    __shared__ __align__(16) unsigned short As[128 * 64];
    __shared__ __align__(16) unsigned short Bs[128 * 64];
    const int flat = blockIdx.x;
    if (flat < 512) {
        Off4 z = {{0, 0, 0, 0}};
        gemm_core<0>(flat, 8, 64, 1, qbf, z, Mt, 0, nullptr, nullptr,
                     tq, z, 1024, 1024, 1.0f, As, Bs);
        return;
    }
    const int t = threadIdx.x;
    const int row = (flat - 512) * 128 + (t >> 1);
    const int half = t & 1;
    const unsigned short* kr = kbf + (long)row * 1024 + half * 512;
    const float* wvp = w2b1 + half * 512;
    float s = 0.f;
#pragma unroll 8
    for (int i = 0; i < 64; i++) {
        union { short8 v8; unsigned short u[8]; } r;
        r.v8 = *(const short8*)(kr + i * 8);
#pragma unroll
        for (int e = 0; e < 8; e++) s += b2f(r.u[e]) * wvp[i * 8 + e];
    }
    s += __shfl_xor(s, 1);
    if (half == 0) vv[row] = s;
}

__global__ void score_kernel(const unsigned short* __restrict__ tq,
                             const unsigned short* __restrict__ kbf,
                             const float* __restrict__ vv,
                             float* __restrict__ partial,
                             unsigned short* __restrict__ scbase,
                             Off4 scoff) {
    __shared__ __align__(16) unsigned short As[128 * 64];
    __shared__ __align__(16) unsigned short Bs[128 * 64];
    const long S = 2048L * 1024;
    Off4 aoff = {{0, S, 2 * S, 3 * S}};
    gemm_core<1>(blockIdx.x, 16, 16, 4, tq, aoff, kbf, S, vv, partial,
                 scbase, scoff, 2048, 1024, 0.02209708691207961f, As, Bs);
}

__global__ void att_kernel(const unsigned short* __restrict__ scbase,
                           Off4 scoff,
                           const unsigned short* __restrict__ vT,
                           float* __restrict__ partial,
                           float* __restrict__ out) {
    __shared__ __align__(16) unsigned short As[128 * 64];
    __shared__ __align__(16) unsigned short Bs[128 * 64];
    const long S = 2048L * 1024;
    Off4 coff = {{0, S, 2 * S, 3 * S}};
    gemm_core<2>(blockIdx.x, 8, 16, 4, scbase, scoff, vT, S, nullptr, partial,
                 out, coff, 1024, 2048, 1.0f, As, Bs);
}

// ---------------------------------------------------------------------------
extern "C" void kernel_launch(void* const* d_in, const int* in_sizes, int n_in,
                              void* d_out, int out_size, void* d_ws, size_t ws_size,
                              hipStream_t stream) {
    const float* q   = (const float*)d_in[0];
    const float* k   = (const float*)d_in[1];
    const float* v   = (const float*)d_in[2];
    const float* W1w = (const float*)d_in[3];
    const float* W1b = (const float*)d_in[4];
    const float* W2w = (const float*)d_in[5];
    const float* W2b = (const float*)d_in[6];
    (void)W2b;  // q-side bias: its score contribution is row-constant, cancels in softmax
    float* out = (float*)d_out;

    char* ws = (char*)d_ws;
    const size_t MB = 1024 * 1024;
    // layout (max 84 MB, R4-proven):
    unsigned short* qbf  = (unsigned short*)(ws + 0);        // 16 MB (dead after tq)
    unsigned short* kbf  = (unsigned short*)(ws + 16 * MB);  // 16 MB (live thru score)
    unsigned short* vT   = (unsigned short*)(ws + 32 * MB);  // 16 MB (live thru att)
    float* partial       = (float*)(ws + 48 * MB);           // 1 MB  (score -> att)
    float* vv            = (float*)(ws + 49 * MB);           // 32 KB (tq -> score)
    float* w2b1          = (float*)(ws + 50 * MB);           // 4 KB  (prep -> tq)
    unsigned short* Mt   = (unsigned short*)(ws + 52 * MB);  // 2 MB  (prep -> tq)
    unsigned short* tq   = (unsigned short*)(ws + 68 * MB);  // 16 MB (tq -> score)
    // sc (32 MB, score -> att) over dead regions: b0/b1 over qbf, b2/b3 over Mt+free
    unsigned short* scb  = (unsigned short*)ws;
    Off4 scoff = {{0, 4L * 1024 * 1024, 26L * 1024 * 1024, 30L * 1024 * 1024}};

    // 1: prep (q/k cast, v transpose, Mt = W2@W1^T, w2b1 = W2@b1)
    prep_kernel<<<16480, 256, 0, stream>>>(q, k, v, W1w, W2w, W1b,
                                           qbf, kbf, vT, Mt, w2b1);
    // 2: tq = qbf @ Mt^T ; vv = kbf @ w2b1
    tq_kernel<<<576, 256, 0, stream>>>(qbf, Mt, kbf, w2b1, tq, vv);
    // 3: sc = exp((tq @ kbf^T + vv) / sqrt(SK)), partial rowsums
    score_kernel<<<1024, 256, 0, stream>>>(tq, kbf, vv, partial, scb, scoff);
    // 4: att = (sc @ vT^T) / rowsum
    att_kernel<<<512, 256, 0, stream>>>(scb, scoff, vT, partial, out);
}

// Round 7
// 304.803 us; speedup vs baseline: 4.4788x; 1.3124x over previous
//
#include <hip/hip_runtime.h>
#include <cmath>
#include <stdint.h>

// ---------------------------------------------------------------------------
// AttentionLayer: att = softmax((q@W1+b1) @ (k@W2+b2)^T / sqrt(Sk)) @ v
// B=4, SQ=SK=2048, D=UNITS=1024, fp32 in/out, bf16 MFMA internally.
// R7: R6 algebra (score = q (W1 W2^T) k^T + vv[col]; b2-term cancels in
//     softmax) in the R4-PROVEN kernel shape: __shared__ declared and used
//     directly inside each __global__ body (R6's device-fn generic-pointer
//     GEMM doubled LDS_Block_Size 32K->64K, halving occupancy -- reverted).
//     4 dispatches: prep(cast/transpose + Mt=W2@W1^T + w2b1) ->
//     tq=q@Mt^T (+vv=k@w2b1) -> score(exp+partials) -> att(/rowsum).
// ---------------------------------------------------------------------------

typedef short short8 __attribute__((ext_vector_type(8)));
typedef float f32x4 __attribute__((ext_vector_type(4)));
typedef __bf16 bf16x8 __attribute__((ext_vector_type(8)));

typedef __attribute__((address_space(3))) void lds_void;
typedef __attribute__((address_space(1))) void gbl_void;

__device__ __forceinline__ unsigned short f2b(float x) {
    unsigned u = __builtin_bit_cast(unsigned, x);
    u += 0x7fffu + ((u >> 16) & 1u);
    return (unsigned short)(u >> 16);
}

struct Off4 { long o[4]; };

__device__ __forceinline__ void load16_to_lds(const unsigned short* g,
                                              unsigned short* l) {
    __builtin_amdgcn_global_load_lds((gbl_void*)g, (lds_void*)l, 16, 0, 0);
}

// ---------------------------------------------------------------------------
// GEMM template: C = A @ Bt^T, 128x128 tile, BK=64 (32 KB LDS), 4 waves
// (2x2), 4x4 of 16x16x32 MFMA per sub-k. LDS XOR swizzle
// (phys chunk = logical ^ (row&7)); XCD-stripe remap over (NX,NY,NZ).
// MODE 0: bf16 out                                             [tq]
// MODE 1: bf16 out = exp((acc+vv[col])*scale), partial slots   [score]
// MODE 2: fp32 out = acc / sum32(partial[row])                 [att]
// NEXTRA > 0: blocks past NX*NY*NZ compute vv[n]=dot(k[n,:],w2b1) (fp32).
// ---------------------------------------------------------------------------
template <int MODE, int NX, int NY, int NZ, int NEXTRA>
__global__ void gemm_tpl(const unsigned short* __restrict__ A0, Off4 aoff,
                         const unsigned short* __restrict__ Bt0, long sB,
                         const float* __restrict__ vvin,
                         float* __restrict__ partial,
                         void* __restrict__ C0, Off4 coff,
                         int N, int K, float scale,
                         const float* __restrict__ kf32,
                         const float* __restrict__ w2b1,
                         float* __restrict__ vvout) {
    __shared__ __align__(16) unsigned short As[128 * 64];
    __shared__ __align__(16) unsigned short Bs[128 * 64];
    const int t = threadIdx.x;

    if (NEXTRA > 0 && (int)blockIdx.x >= NX * NY * NZ) {
        // ---- vv[n] = dot(k[n,:], w2b1), 128 rows/block, 2 thr/row ----
        const int row = ((int)blockIdx.x - NX * NY * NZ) * 128 + (t >> 1);
        const int half = t & 1;
        const float* kr = kf32 + (long)row * 1024 + half * 512;
        const float* wp = w2b1 + half * 512;
        float s = 0.f;
#pragma unroll 8
        for (int i = 0; i < 128; i++) {
            float4 kv = *(const float4*)(kr + i * 4);
            float4 wv = *(const float4*)(wp + i * 4);
            s += kv.x * wv.x + kv.y * wv.y + kv.z * wv.z + kv.w * wv.w;
        }
        s += __shfl_xor(s, 1);
        if (half == 0) vvout[row] = s;
        return;
    }

    // ---- XCD-aware tile remap (Rt = NY*NZ divisible by 8) ----
    int bx, by, bz;
    {
        const int Rt = NY * NZ;
        const int rpx = Rt >> 3;
        const int flat = blockIdx.x;
        const int c = flat & 7;
        const int j = flat >> 3;
        bx = j / rpx;
        const int yg = c * rpx + (j - bx * rpx);
        bz = yg / NY;
        by = yg - bz * NY;
    }
    const unsigned short* A  = A0  + aoff.o[bz];
    const unsigned short* Bt = Bt0 + (long)bz * sB;

    const int lane = t & 63;
    const int wave = t >> 6;
    const int wm = wave >> 1, wn = wave & 1;
    const int row0 = by * 128;
    const int col0 = bx * 128;

    // staging: lane l -> row group l>>3, phys chunk l&7; source chunk XOR'd
    const int rS = lane >> 3;
    const int kOffS = ((lane & 7) ^ rS) * 8;
    const unsigned short* gA[4];
    const unsigned short* gB[4];
    unsigned short* lA[4];
    unsigned short* lB[4];
#pragma unroll
    for (int i = 0; i < 4; i++) {
        const int rowl = i * 32 + wave * 8 + rS;
        const int ldsrow = i * 32 + wave * 8;
        gA[i] = A  + (long)(row0 + rowl) * K + kOffS;
        gB[i] = Bt + (long)(col0 + rowl) * K + kOffS;
        lA[i] = As + ldsrow * 64;
        lB[i] = Bs + ldsrow * 64;
    }

    const int lr = lane & 15;
    const int quad = lane >> 4;
    const int pc0 = (quad ^ (lr & 7)) * 8;
    const int pc1 = ((4 + quad) ^ (lr & 7)) * 8;

    f32x4 acc[4][4];
#pragma unroll
    for (int i = 0; i < 4; i++)
#pragma unroll
        for (int j = 0; j < 4; j++) acc[i][j] = f32x4{0.f, 0.f, 0.f, 0.f};

    for (int k0 = 0; k0 < K; k0 += 64) {
#pragma unroll
        for (int i = 0; i < 4; i++) {
            load16_to_lds(gA[i] + k0, lA[i]);
            load16_to_lds(gB[i] + k0, lB[i]);
        }
        __syncthreads();
#pragma unroll
        for (int ks = 0; ks < 2; ks++) {
            const int pc = ks ? pc1 : pc0;
            bf16x8 a[4], b[4];
#pragma unroll
            for (int i = 0; i < 4; i++) {
                a[i] = __builtin_bit_cast(bf16x8,
                    *(const short8*)(As + (wm * 64 + i * 16 + lr) * 64 + pc));
                b[i] = __builtin_bit_cast(bf16x8,
                    *(const short8*)(Bs + (wn * 64 + i * 16 + lr) * 64 + pc));
            }
#pragma unroll
            for (int i = 0; i < 4; i++)
#pragma unroll
                for (int j = 0; j < 4; j++)
                    acc[i][j] = __builtin_amdgcn_mfma_f32_16x16x32_bf16(
                        a[i], b[j], acc[i][j], 0, 0, 0);
        }
        __syncthreads();
    }

    // ---- epilogue (C/D layout: col = lane&15, row = quad*4 + reg) ----
    const long cbase = coff.o[bz];

    if (MODE == 0) {
#pragma unroll
        for (int j = 0; j < 4; j++) {
            const int gcol = col0 + wn * 64 + j * 16 + lr;
#pragma unroll
            for (int i = 0; i < 4; i++) {
                const int growb = row0 + wm * 64 + i * 16 + quad * 4;
#pragma unroll
                for (int r = 0; r < 4; r++)
                    ((unsigned short*)C0)[cbase + (long)(growb + r) * N + gcol] =
                        f2b(acc[i][j][r]);
            }
        }
    } else if (MODE == 1) {
        float psum[4][4];
#pragma unroll
        for (int i = 0; i < 4; i++)
#pragma unroll
            for (int r = 0; r < 4; r++) psum[i][r] = 0.f;
#pragma unroll
        for (int j = 0; j < 4; j++) {
            const int gcol = col0 + wn * 64 + j * 16 + lr;
            const float vvv = vvin[(long)bz * 2048 + gcol];
#pragma unroll
            for (int i = 0; i < 4; i++) {
                const int growb = row0 + wm * 64 + i * 16 + quad * 4;
#pragma unroll
                for (int r = 0; r < 4; r++) {
                    float e = __expf((acc[i][j][r] + vvv) * scale);
                    psum[i][r] += e;
                    ((unsigned short*)C0)[cbase + (long)(growb + r) * N + gcol] = f2b(e);
                }
            }
        }
#pragma unroll
        for (int i = 0; i < 4; i++)
#pragma unroll
            for (int r = 0; r < 4; r++) {
                float s = psum[i][r];
                s += __shfl_xor(s, 1);
                s += __shfl_xor(s, 2);
                s += __shfl_xor(s, 4);
                s += __shfl_xor(s, 8);
                if (lr == 0) {
                    const int grow = row0 + wm * 64 + i * 16 + quad * 4 + r;
                    partial[((long)bz * 2048 + grow) * 32 + bx * 2 + wn] = s;
                }
            }
    } else {  // MODE == 2
        float* rowinv = (float*)(void*)As;
        if (t < 128) {
            const float* pr = partial + ((long)bz * 2048 + row0 + t) * 32;
            float s = 0.f;
#pragma unroll
            for (int c4 = 0; c4 < 32; c4 += 4) {
                float4 v4 = *(const float4*)(pr + c4);
                s += v4.x + v4.y + v4.z + v4.w;
            }
            rowinv[t] = 1.0f / s;
        }
        __syncthreads();
#pragma unroll
        for (int i = 0; i < 4; i++) {
            const int lrow = wm * 64 + i * 16 + quad * 4;
#pragma unroll
            for (int r = 0; r < 4; r++) {
                const float inv = rowinv[lrow + r];
#pragma unroll
                for (int j = 0; j < 4; j++) {
                    const int gcol = col0 + wn * 64 + j * 16 + lr;
                    ((float*)C0)[cbase + (long)(row0 + lrow + r) * N + gcol] =
                        acc[i][j][r] * inv;
                }
            }
        }
    }
}

// ---------------------------------------------------------------------------
// prep kernel: grid x = 16480.
//   0..63    : Mt = W2 @ W1^T  (fp32 hybrid staging, bf16 MFMA, 128x128)
//   64..95   : w2b1[d'] = dot(W2[d',:], b1)
//   96..8287 : v batch transpose  [2048][1024] -> vT [1024][2048] bf16
//   8288..   : q,k fp32 -> bf16 casts (4096 blocks each)
// ---------------------------------------------------------------------------
__global__ void prep_kernel(const float* __restrict__ q,
                            const float* __restrict__ k,
                            const float* __restrict__ v,
                            const float* __restrict__ W1,
                            const float* __restrict__ W2,
                            const float* __restrict__ b1,
                            unsigned short* __restrict__ qbf,
                            unsigned short* __restrict__ kbf,
                            unsigned short* __restrict__ vT,
                            unsigned short* __restrict__ Mt,
                            float* __restrict__ w2b1) {
    __shared__ __align__(16) unsigned short As[128 * 64];
    __shared__ __align__(16) unsigned short Bs[128 * 64];
    const int flat = blockIdx.x;
    const int t = threadIdx.x;

    if (flat < 64) {
        // ---- Mt GEMM: Mt[n,d] = sum_u W2[n,u] * W1[d,u] ----
        const int by = flat >> 3, bx = flat & 7;
        const int row0 = by * 128, col0 = bx * 128;
        const int lane = t & 63, wave = t >> 6;
        const int wm = wave >> 1, wn = wave & 1;
        const int lr = lane & 15, quad = lane >> 4;
        const int srow = t >> 1;            // 0..127
        const int hk = (t & 1) * 32;        // fp32 elems 0 or 32
        const float* gA = W2 + (long)(row0 + srow) * 1024 + hk;
        const float* gB = W1 + (long)(col0 + srow) * 1024 + hk;
        unsigned short* lA = As + srow * 64;
        unsigned short* lB = Bs + srow * 64;
        const int xr = srow & 7;
        const int pc0 = (quad ^ (lr & 7)) * 8;
        const int pc1 = ((4 + quad) ^ (lr & 7)) * 8;

        f32x4 acc[4][4];
#pragma unroll
        for (int i = 0; i < 4; i++)
#pragma unroll
            for (int j = 0; j < 4; j++) acc[i][j] = f32x4{0.f, 0.f, 0.f, 0.f};

        for (int k0 = 0; k0 < 1024; k0 += 64) {
#pragma unroll
            for (int m2 = 0; m2 < 2; m2++) {
                const float* src = m2 ? gB : gA;
                unsigned short* dst = m2 ? lB : lA;
#pragma unroll
                for (int ci = 0; ci < 4; ci++) {
                    float4 f0 = *(const float4*)(src + k0 + ci * 8);
                    float4 f1 = *(const float4*)(src + k0 + ci * 8 + 4);
                    union { short8 v8; unsigned short u[8]; } r;
                    r.u[0] = f2b(f0.x); r.u[1] = f2b(f0.y);
                    r.u[2] = f2b(f0.z); r.u[3] = f2b(f0.w);
                    r.u[4] = f2b(f1.x); r.u[5] = f2b(f1.y);
                    r.u[6] = f2b(f1.z); r.u[7] = f2b(f1.w);
                    const int phys = ((hk >> 3) + ci) ^ xr;
                    *(short8*)(dst + phys * 8) = r.v8;
                }
            }
            __syncthreads();
#pragma unroll
            for (int ks = 0; ks < 2; ks++) {
                const int pc = ks ? pc1 : pc0;
                bf16x8 a[4], b[4];
#pragma unroll
                for (int i = 0; i < 4; i++) {
                    a[i] = __builtin_bit_cast(bf16x8,
                        *(const short8*)(As + (wm * 64 + i * 16 + lr) * 64 + pc));
                    b[i] = __builtin_bit_cast(bf16x8,
                        *(const short8*)(Bs + (wn * 64 + i * 16 + lr) * 64 + pc));
                }
#pragma unroll
                for (int i = 0; i < 4; i++)
#pragma unroll
                    for (int j = 0; j < 4; j++)
                        acc[i][j] = __builtin_amdgcn_mfma_f32_16x16x32_bf16(
                            a[i], b[j], acc[i][j], 0, 0, 0);
            }
            __syncthreads();
        }
#pragma unroll
        for (int j = 0; j < 4; j++) {
            const int gcol = col0 + wn * 64 + j * 16 + lr;
#pragma unroll
            for (int i = 0; i < 4; i++) {
                const int growb = row0 + wm * 64 + i * 16 + quad * 4;
#pragma unroll
                for (int r = 0; r < 4; r++)
                    Mt[(long)(growb + r) * 1024 + gcol] = f2b(acc[i][j][r]);
            }
        }
        return;
    }
    if (flat < 96) {
        // ---- w2b1 = W2 @ b1 ----
        const int b = flat - 64;
        const int row = b * 32 + (t >> 3);
        const int oct = t & 7;
        const float* wr = W2 + (long)row * 1024 + oct * 128;
        const float* br = b1 + oct * 128;
        float s = 0.f;
#pragma unroll
        for (int i = 0; i < 32; i++) {
            float4 w = *(const float4*)(wr + i * 4);
            float4 bb = *(const float4*)(br + i * 4);
            s += w.x * bb.x + w.y * bb.y + w.z * bb.z + w.w * bb.w;
        }
        s += __shfl_xor(s, 1);
        s += __shfl_xor(s, 2);
        s += __shfl_xor(s, 4);
        if (oct == 0) w2b1[row] = s;
        return;
    }
    const int u = flat - 96;
    if (u < 8192) {
        // ---- v transpose: [2048][1024] -> [1024][2048] ----
        float (*tile)[33] = (float (*)[33])(void*)As;
        const int vz = u >> 11;
        const int rem = u & 2047;
        const int vy = rem >> 6, vx = rem & 63;
        const float* in = v + (long)vz * 2048 * 1024;
        unsigned short* outp = vT + (long)vz * 1024 * 2048;
        const int rt = vx * 32, ct = vy * 32;
        {
            int r = t >> 3, c4 = (t & 7) * 4;
            float4 a = *(const float4*)(in + (long)(rt + r) * 1024 + ct + c4);
            tile[r][c4 + 0] = a.x; tile[r][c4 + 1] = a.y;
            tile[r][c4 + 2] = a.z; tile[r][c4 + 3] = a.w;
        }
        __syncthreads();
        {
            int c = t >> 3, rg = (t & 7) * 4;
            ushort4 o;
            o.x = f2b(tile[rg + 0][c]); o.y = f2b(tile[rg + 1][c]);
            o.z = f2b(tile[rg + 2][c]); o.w = f2b(tile[rg + 3][c]);
            *(ushort4*)(outp + (long)(ct + c) * 2048 + rt + rg) = o;
        }
        return;
    }
    // ---- q/k casts: 2048 elems per block ----
    const int c = u - 8192;
    const float* in = (c < 4096) ? q : k;
    unsigned short* outp = (c < 4096) ? qbf : kbf;
    const long i = (((long)(c & 4095)) * 256 + t) * 8;
    float4 a = *(const float4*)(in + i);
    float4 b = *(const float4*)(in + i + 4);
    union { short8 v8; unsigned short uu[8]; } r;
    r.uu[0] = f2b(a.x); r.uu[1] = f2b(a.y); r.uu[2] = f2b(a.z); r.uu[3] = f2b(a.w);
    r.uu[4] = f2b(b.x); r.uu[5] = f2b(b.y); r.uu[6] = f2b(b.z); r.uu[7] = f2b(b.w);
    *(short8*)(outp + i) = r.v8;
}

// ---------------------------------------------------------------------------
extern "C" void kernel_launch(void* const* d_in, const int* in_sizes, int n_in,
                              void* d_out, int out_size, void* d_ws, size_t ws_size,
                              hipStream_t stream) {
    const float* q   = (const float*)d_in[0];
    const float* k   = (const float*)d_in[1];
    const float* v   = (const float*)d_in[2];
    const float* W1w = (const float*)d_in[3];
    const float* W1b = (const float*)d_in[4];
    const float* W2w = (const float*)d_in[5];
    const float* W2b = (const float*)d_in[6];
    (void)W2b;  // b2's score term is row-constant -> cancels in softmax
    float* out = (float*)d_out;

    char* ws = (char*)d_ws;
    const size_t MB = 1024 * 1024;
    unsigned short* qbf  = (unsigned short*)(ws + 0);        // 16 MB (dead after tq)
    unsigned short* kbf  = (unsigned short*)(ws + 16 * MB);  // 16 MB (thru score)
    unsigned short* vT   = (unsigned short*)(ws + 32 * MB);  // 16 MB (thru att)
    float* partial       = (float*)(ws + 48 * MB);           // 1 MB  (score->att)
    float* vv            = (float*)(ws + 49 * MB);           // 32 KB (tq->score)
    float* w2b1          = (float*)(ws + 50 * MB);           // 4 KB  (prep->tq)
    unsigned short* Mt   = (unsigned short*)(ws + 52 * MB);  // 2 MB  (prep->tq)
    unsigned short* tq   = (unsigned short*)(ws + 68 * MB);  // 16 MB (tq->score)
    // sc (32 MB, score->att) over dead regions: b0/b1 over qbf, b2 over Mt,
    // b3 over free space (elem offsets)
    unsigned short* scb  = (unsigned short*)ws;
    Off4 scoff = {{0, 4L * 1024 * 1024, 26L * 1024 * 1024, 30L * 1024 * 1024}};
    const long S = 2L * 1024 * 1024;
    Off4 offS = {{0, S, 2 * S, 3 * S}};
    Off4 z4 = {{0, 0, 0, 0}};

    // 1: prep (q/k cast, v transpose, Mt = W2@W1^T, w2b1 = W2@b1)
    prep_kernel<<<16480, 256, 0, stream>>>(q, k, v, W1w, W2w, W1b,
                                           qbf, kbf, vT, Mt, w2b1);
    // 2: tq = qbf @ Mt^T ; vv = k @ w2b1 (fp32)
    gemm_tpl<0, 8, 64, 1, 64><<<576, 256, 0, stream>>>(
        qbf, z4, Mt, 0, nullptr, nullptr, tq, z4, 1024, 1024, 1.0f,
        k, w2b1, vv);
    // 3: sc = exp((tq @ kbf^T + vv) / sqrt(SK)), partial rowsums
    gemm_tpl<1, 16, 16, 4, 0><<<1024, 256, 0, stream>>>(
        tq, offS, kbf, S, vv, partial, scb, scoff, 2048, 1024,
        0.02209708691207961f, nullptr, nullptr, nullptr);
    // 4: att = (sc @ vT^T) / rowsum
    gemm_tpl<2, 8, 16, 4, 0><<<512, 256, 0, stream>>>(
        scb, scoff, vT, S, nullptr, partial, out, offS, 1024, 2048, 1.0f,
        nullptr, nullptr, nullptr);
}